// Round 4
// baseline (445.862 us; speedup 1.0000x reference)
//
#include <hip/hip_runtime.h>
#include <math.h>

// GCN: out = softmax( S·relu((S·h)W1 + b1) · W2 + b2 ),  S = in-edge sum + self-loop.
// Round 4: fill_csr (90us, 83MB writeback for 4.8MB of data -- 16x partial-line
// amplification from temporally/XCD-scattered 4B stores) replaced by a bucketed
// two-pass fill: XCD-class-replicated segment append (dense, line-local writes)
// then per-bucket LDS-cursor scatter within a 6KB window.

constexpr int N = 100000;
constexpr int E = 1200000;
constexpr int D = 64;    // input dim
constexpr int H = 128;   // hidden
constexpr int C = 40;    // classes
constexpr int NB_SCAN = (N + 255) / 256;        // 391 scan blocks
constexpr int NBUCK   = (N + 127) / 128;        // 782 dst-buckets of 128 nodes
constexpr int NSEG    = NBUCK * 8;              // 6256 (bucket x replica) segments

// ---------------- degree + bucket-segment histogram ----------------
__global__ __launch_bounds__(256) void histo(const int* __restrict__ adj,
                                             int* __restrict__ deg,
                                             int* __restrict__ cnt) {
    int e = blockIdx.x * 256 + threadIdx.x;
    if (e < E) {
        int dst = adj[2 * e + 1];
        atomicAdd(&deg[dst], 1);
        int b = dst >> 7;
        int r = (e >> 8) & 7;            // must match append's blockIdx&7
        atomicAdd(&cnt[b * 8 + r], 1);
    }
}

// ---------------- row_start scan (over deg) ----------------
__global__ __launch_bounds__(256) void scan1(const int* __restrict__ deg,
                                             int* __restrict__ incl,
                                             int* __restrict__ bsum) {
    __shared__ int s[256];
    int i = blockIdx.x * 256 + threadIdx.x;
    int v = (i < N) ? deg[i] : 0;
    s[threadIdx.x] = v;
    __syncthreads();
    for (int off = 1; off < 256; off <<= 1) {
        int x = (threadIdx.x >= (unsigned)off) ? s[threadIdx.x - off] : 0;
        __syncthreads();
        s[threadIdx.x] += x;
        __syncthreads();
    }
    if (i < N) incl[i] = s[threadIdx.x];
    if (threadIdx.x == 255) bsum[blockIdx.x] = s[255];
}

__global__ __launch_bounds__(512) void scan2(int* __restrict__ bsum) {
    __shared__ int s[512];
    int t = threadIdx.x;
    int v = (t < NB_SCAN) ? bsum[t] : 0;
    s[t] = v;
    __syncthreads();
    for (int off = 1; off < 512; off <<= 1) {
        int x = (t >= off) ? s[t - off] : 0;
        __syncthreads();
        s[t] += x;
        __syncthreads();
    }
    if (t < NB_SCAN) bsum[t] = s[t] - v;   // exclusive
}

__global__ __launch_bounds__(256) void scan3(int* __restrict__ row_start,   // holds incl
                                             const int* __restrict__ deg,
                                             const int* __restrict__ bsum) {
    int i = blockIdx.x * 256 + threadIdx.x;
    if (i < N) row_start[i] = row_start[i] - deg[i] + bsum[blockIdx.x];
}

// ---------------- segment scan: exclusive scan of cnt[NSEG] -> segstart, segcur ----
__global__ __launch_bounds__(1024) void scan_seg(const int* __restrict__ cnt,
                                                 int* __restrict__ segstart,
                                                 int* __restrict__ segcur) {
    __shared__ int s[1024];
    int t = threadIdx.x;
    int base = t * 7;
    int local[7];
    int sum = 0;
#pragma unroll
    for (int i = 0; i < 7; ++i) {
        int idx = base + i;
        int v = (idx < NSEG) ? cnt[idx] : 0;
        local[i] = sum;
        sum += v;
    }
    s[t] = sum;
    __syncthreads();
    for (int off = 1; off < 1024; off <<= 1) {
        int x = (t >= off) ? s[t - off] : 0;
        __syncthreads();
        s[t] += x;
        __syncthreads();
    }
    int prev = t ? s[t - 1] : 0;
#pragma unroll
    for (int i = 0; i < 7; ++i) {
        int idx = base + i;
        if (idx < NSEG) {
            int v = prev + local[i];
            segstart[idx] = v;
            segcur[idx]   = v;
        }
    }
    if (t == 1023) segstart[NSEG] = s[1023];   // total = E
}

// ---------------- append: edge -> packed word in its (bucket, class) segment -------
__global__ __launch_bounds__(256) void append_seg(const int* __restrict__ adj,
                                                  int* __restrict__ segcur,
                                                  int* __restrict__ staging) {
    int e = blockIdx.x * 256 + threadIdx.x;
    if (e < E) {
        int src = adj[2 * e];
        int dst = adj[2 * e + 1];
        int b = dst >> 7;
        int r = blockIdx.x & 7;          // == (e>>8)&7
        int p = atomicAdd(&segcur[b * 8 + r], 1);
        staging[p] = (src << 7) | (dst & 127);
    }
}

// ---------------- bucket fill: LDS cursors, scatter within 6KB csr window ----------
__global__ __launch_bounds__(256) void fill_bucket(const int* __restrict__ staging,
                                                   const int* __restrict__ segstart,
                                                   const int* __restrict__ row_start,
                                                   int* __restrict__ csr) {
    __shared__ int cur[128];
    int b = blockIdx.x;
    int nbase = b << 7;
    if (threadIdx.x < 128) {
        int node = nbase + threadIdx.x;
        cur[threadIdx.x] = (node < N) ? row_start[node] : 0;
    }
    __syncthreads();
    int lo = segstart[b * 8];
    int hi = segstart[b * 8 + 8];       // contiguous: replicas are consecutive
    for (int i = lo + threadIdx.x; i < hi; i += 256) {
        int w = staging[i];
        int p = atomicAdd(&cur[w & 127], 1);
        csr[p] = w >> 7;
    }
}

// ---------------- layer-1 gather: agg[node] = h[node] + sum_{in-edges} h[src] ------
__global__ __launch_bounds__(256) void gather1(const float* __restrict__ h,
                                               const int* __restrict__ csr,
                                               const int* __restrict__ row_start,
                                               const int* __restrict__ deg,
                                               float* __restrict__ agg) {
    int node = blockIdx.x * 4 + (threadIdx.x >> 6);
    int lane = threadIdx.x & 63;
    float acc = h[node * D + lane];            // self-loop
    int rs = row_start[node], d = deg[node];
    int j = 0;
    for (; j + 4 <= d; j += 4) {
        int s0 = csr[rs + j], s1 = csr[rs + j + 1];
        int s2 = csr[rs + j + 2], s3 = csr[rs + j + 3];
        acc += h[s0 * D + lane];
        acc += h[s1 * D + lane];
        acc += h[s2 * D + lane];
        acc += h[s3 * D + lane];
    }
    for (; j < d; ++j) acc += h[csr[rs + j] * D + lane];
    agg[node * D + lane] = acc;
}

// ---------------- X = relu(agg @ W1 + b1), tiled ----------------
__global__ __launch_bounds__(256) void gemm1_relu(const float* __restrict__ A,
                                                  const float* __restrict__ W1,
                                                  const float* __restrict__ b1,
                                                  float* __restrict__ X) {
    __shared__ float w_s[D * H];      // 32 KB, [k][col]
    __shared__ float a_s[16 * D];     // 4 KB,  [row][k]
    int row0 = blockIdx.x * 16;
    {
        const float4* src = (const float4*)W1;
        float4* dst = (float4*)w_s;
#pragma unroll
        for (int i = 0; i < 8; ++i)
            dst[threadIdx.x + i * 256] = src[threadIdx.x + i * 256];
    }
    {
        int r = threadIdx.x >> 4;
        int q = threadIdx.x & 15;
        float4 v = *(const float4*)&A[(row0 + r) * D + q * 4];
        *(float4*)&a_s[r * D + q * 4] = v;
    }
    __syncthreads();

    int tr   = threadIdx.x >> 6;
    int lane = threadIdx.x & 63;
    float acc[4][2] = {};
#pragma unroll
    for (int k = 0; k < D; ++k) {
        float b0 = w_s[k * H + lane];
        float b1v = w_s[k * H + lane + 64];
#pragma unroll
        for (int i = 0; i < 4; ++i) {
            float a = a_s[(tr + 4 * i) * D + k];
            acc[i][0] = fmaf(a, b0, acc[i][0]);
            acc[i][1] = fmaf(a, b1v, acc[i][1]);
        }
    }
    float bias0 = b1[lane], bias1 = b1[lane + 64];
#pragma unroll
    for (int i = 0; i < 4; ++i) {
        int row = row0 + tr + 4 * i;
        X[row * H + lane]      = fmaxf(acc[i][0] + bias0, 0.f);
        X[row * H + lane + 64] = fmaxf(acc[i][1] + bias1, 0.f);
    }
}

// ---------------- Z = X @ W2, tiled ----------------
constexpr int XS = 132;
__global__ __launch_bounds__(256) void gemm2(const float* __restrict__ X,
                                             const float* __restrict__ W2,
                                             float* __restrict__ Z) {
    __shared__ float w_s[H * C];        // 20 KB
    __shared__ float x_s[64 * XS];      // 33.8 KB
    int row0 = blockIdx.x * 64;
    {
        const float4* src = (const float4*)W2;
        float4* dst = (float4*)w_s;
#pragma unroll
        for (int i = 0; i < 5; ++i)
            dst[threadIdx.x + i * 256] = src[threadIdx.x + i * 256];
    }
    {
#pragma unroll
        for (int i = 0; i < 8; ++i) {
            int idx = threadIdx.x + i * 256;
            int r = idx >> 5;
            int q = idx & 31;
            int grow = row0 + r;
            if (grow >= N) grow = N - 1;
            float4 v = *(const float4*)&X[grow * H + q * 4];
            *(float4*)&x_s[r * XS + q * 4] = v;
        }
    }
    __syncthreads();

    int tc   = threadIdx.x & 7;
    int trow = threadIdx.x >> 3;
    float acc[2][5] = {};
#pragma unroll 4
    for (int k = 0; k < H; ++k) {
        float b[5];
#pragma unroll
        for (int j = 0; j < 5; ++j) b[j] = w_s[k * C + tc * 5 + j];
        float a0 = x_s[(trow * 2) * XS + k];
        float a1 = x_s[(trow * 2 + 1) * XS + k];
#pragma unroll
        for (int j = 0; j < 5; ++j) {
            acc[0][j] = fmaf(a0, b[j], acc[0][j]);
            acc[1][j] = fmaf(a1, b[j], acc[1][j]);
        }
    }
#pragma unroll
    for (int i = 0; i < 2; ++i) {
        int row = row0 + trow * 2 + i;
        if (row < N) {
#pragma unroll
            for (int j = 0; j < 5; ++j)
                Z[row * C + tc * 5 + j] = acc[i][j];
        }
    }
}

// ---------------- out[node] = softmax(Z[node] + sum Z[src] + b2) ----------------
__global__ __launch_bounds__(256) void gather2_softmax(const float* __restrict__ Z,
                                                       const int* __restrict__ csr,
                                                       const int* __restrict__ row_start,
                                                       const int* __restrict__ deg,
                                                       const float* __restrict__ b2,
                                                       float* __restrict__ out) {
    int node = blockIdx.x * 4 + (threadIdx.x >> 6);
    int lane = threadIdx.x & 63;
    int rs = row_start[node], d = deg[node];
    float acc = (lane < C) ? Z[node * C + lane] : 0.f;   // self-loop
    int j = 0;
    for (; j + 4 <= d; j += 4) {
        int s0 = csr[rs + j], s1 = csr[rs + j + 1];
        int s2 = csr[rs + j + 2], s3 = csr[rs + j + 3];
        if (lane < C) {
            acc += Z[s0 * C + lane];
            acc += Z[s1 * C + lane];
            acc += Z[s2 * C + lane];
            acc += Z[s3 * C + lane];
        }
    }
    for (; j < d; ++j) {
        int s = csr[rs + j];
        if (lane < C) acc += Z[s * C + lane];
    }
    float v = (lane < C) ? acc + b2[lane] : -INFINITY;
    float m = v;
    for (int off = 32; off; off >>= 1) m = fmaxf(m, __shfl_xor(m, off));
    float ex = (lane < C) ? expf(v - m) : 0.f;
    float ssum = ex;
    for (int off = 32; off; off >>= 1) ssum += __shfl_xor(ssum, off);
    if (lane < C) out[node * C + lane] = ex / ssum;
}

extern "C" void kernel_launch(void* const* d_in, const int* in_sizes, int n_in,
                              void* d_out, int out_size, void* d_ws, size_t ws_size,
                              hipStream_t stream) {
    const float* h   = (const float*)d_in[0];   // N*D
    const int*   adj = (const int*)  d_in[1];   // E*2
    const float* W1  = (const float*)d_in[2];   // D*H
    const float* b1  = (const float*)d_in[3];   // H
    const float* W2  = (const float*)d_in[4];   // H*C
    const float* b2  = (const float*)d_in[5];   // C
    float* out = (float*)d_out;                 // N*C fp32

    // workspace layout
    float* agg1      = (float*)d_ws;                    // N*D
    float* X         = agg1 + (size_t)N * D;            // N*H
    float* Z         = X    + (size_t)N * H;            // N*C
    int*   deg       = (int*)(Z + (size_t)N * C);       // N
    int*   cnt       = deg + N;                         // NSEG   (memset with deg)
    int*   row_start = cnt + NSEG;                      // N
    int*   bsum      = row_start + N;                   // 512
    int*   segstart  = bsum + 512;                      // NSEG+1
    int*   segcur    = segstart + NSEG + 1;             // NSEG
    int*   staging   = segcur + NSEG;                   // E
    int*   csr       = staging + E;                     // E

    hipMemsetAsync(deg, 0, (N + NSEG) * sizeof(int), stream);
    histo      <<<(E + 255) / 256, 256, 0, stream>>>(adj, deg, cnt);
    scan1      <<<NB_SCAN, 256, 0, stream>>>(deg, row_start, bsum);
    scan2      <<<1, 512, 0, stream>>>(bsum);
    scan3      <<<NB_SCAN, 256, 0, stream>>>(row_start, deg, bsum);
    scan_seg   <<<1, 1024, 0, stream>>>(cnt, segstart, segcur);
    append_seg <<<(E + 255) / 256, 256, 0, stream>>>(adj, segcur, staging);
    fill_bucket<<<NBUCK, 256, 0, stream>>>(staging, segstart, row_start, csr);

    gather1        <<<N / 4, 256, 0, stream>>>(h, csr, row_start, deg, agg1);
    gemm1_relu     <<<N / 16, 256, 0, stream>>>(agg1, W1, b1, X);
    gemm2          <<<(N + 63) / 64, 256, 0, stream>>>(X, W2, Z);
    gather2_softmax<<<N / 4, 256, 0, stream>>>(Z, csr, row_start, deg, b2, out);
}

// Round 5
// 354.892 us; speedup vs baseline: 1.2563x; 1.2563x over previous
//
#include <hip/hip_runtime.h>
#include <math.h>

// GCN: out = softmax( S·relu((S·h)W1 + b1) · W2 + b2 ),  S = in-edge sum + self-loop.
// Round 5: kill per-edge global atomics in CSR build. LDS-histogram + dense partials
// (no atomics) for bucket counts; deg/row_start derived inside fill_bucket via LDS
// count+scan (scan1/2/3 and the 103us deg histogram deleted).

constexpr int N = 100000;
constexpr int E = 1200000;
constexpr int D = 64;    // input dim
constexpr int H = 128;   // hidden
constexpr int C = 40;    // classes
constexpr int NBUCK = (N + 127) / 128;          // 782 dst-buckets of 128 nodes
constexpr int NSEG  = NBUCK * 8;                // 6256 (bucket x replica) segments
constexpr int EBLK  = 2048;                     // edges per histo/append block
constexpr int NHB   = (E + EBLK - 1) / EBLK;    // 586 edge blocks

// ---- per-block LDS bucket histogram, dense dump (no global atomics) ----
__global__ __launch_bounds__(256) void histo_cnt(const int* __restrict__ adj,
                                                 int* __restrict__ partial) {
    __shared__ int cnt[NBUCK];
    for (int i = threadIdx.x; i < NBUCK; i += 256) cnt[i] = 0;
    __syncthreads();
    int base = blockIdx.x * EBLK + threadIdx.x * 8;
    const int2* edges = (const int2*)adj;
#pragma unroll
    for (int i = 0; i < 8; ++i) {
        int e = base + i;
        if (e < E) atomicAdd(&cnt[edges[e].y >> 7], 1);
    }
    __syncthreads();
    int* dst = partial + blockIdx.x * NBUCK;
    for (int i = threadIdx.x; i < NBUCK; i += 256) dst[i] = cnt[i];
}

// ---- cnt[b*8+r] = sum over edge-blocks of class r of partial[blk][b] ----
__global__ __launch_bounds__(256) void reduce_cnt(const int* __restrict__ partial,
                                                  int* __restrict__ cnt) {
    int seg = blockIdx.x * 256 + threadIdx.x;
    if (seg < NSEG) {
        int b = seg >> 3, r = seg & 7;
        int s = 0;
        for (int blk = r; blk < NHB; blk += 8) s += partial[blk * NBUCK + b];
        cnt[seg] = s;
    }
}

// ---- exclusive scan of cnt[NSEG] -> segstart, segcur ----
__global__ __launch_bounds__(1024) void scan_seg(const int* __restrict__ cnt,
                                                 int* __restrict__ segstart,
                                                 int* __restrict__ segcur) {
    __shared__ int s[1024];
    int t = threadIdx.x;
    int base = t * 7;
    int local[7];
    int sum = 0;
#pragma unroll
    for (int i = 0; i < 7; ++i) {
        int idx = base + i;
        int v = (idx < NSEG) ? cnt[idx] : 0;
        local[i] = sum;
        sum += v;
    }
    s[t] = sum;
    __syncthreads();
    for (int off = 1; off < 1024; off <<= 1) {
        int x = (t >= off) ? s[t - off] : 0;
        __syncthreads();
        s[t] += x;
        __syncthreads();
    }
    int prev = t ? s[t - 1] : 0;
#pragma unroll
    for (int i = 0; i < 7; ++i) {
        int idx = base + i;
        if (idx < NSEG) {
            int v = prev + local[i];
            segstart[idx] = v;
            segcur[idx]   = v;
        }
    }
    if (t == 1023) segstart[NSEG] = s[1023];   // total = E
}

// ---- append: edge -> packed (src<<7|dst_local) in its (bucket, class) segment ----
__global__ __launch_bounds__(256) void append_seg(const int* __restrict__ adj,
                                                  int* __restrict__ segcur,
                                                  int* __restrict__ staging) {
    int base = blockIdx.x * EBLK + threadIdx.x * 8;
    int r = blockIdx.x & 7;
    const int2* edges = (const int2*)adj;
#pragma unroll
    for (int i = 0; i < 8; ++i) {
        int e = base + i;
        if (e < E) {
            int2 ed = edges[e];
            int b = ed.y >> 7;
            int p = atomicAdd(&segcur[b * 8 + r], 1);
            staging[p] = (ed.x << 7) | (ed.y & 127);
        }
    }
}

// ---- per-bucket: count -> deg/row_start (LDS scan), then scatter csr in window ----
__global__ __launch_bounds__(256) void fill_bucket2(const int* __restrict__ staging,
                                                    const int* __restrict__ segstart,
                                                    int* __restrict__ deg,
                                                    int* __restrict__ row_start,
                                                    int* __restrict__ csr) {
    __shared__ int cnt[128], cur[128], s[128];
    int b = blockIdx.x;
    int t = threadIdx.x;
    if (t < 128) cnt[t] = 0;
    __syncthreads();
    int lo = segstart[b * 8];
    int hi = segstart[b * 8 + 8];       // replicas of a bucket are consecutive
    for (int i = lo + t; i < hi; i += 256)
        atomicAdd(&cnt[staging[i] & 127], 1);
    __syncthreads();
    int v = (t < 128) ? cnt[t] : 0;
    if (t < 128) s[t] = v;
    __syncthreads();
    for (int off = 1; off < 128; off <<= 1) {
        int x = (t < 128 && t >= off) ? s[t - off] : 0;
        __syncthreads();
        if (t < 128) s[t] += x;
        __syncthreads();
    }
    if (t < 128) {
        int ex = s[t] - v;              // exclusive prefix within bucket
        cur[t] = ex;
        int node = (b << 7) + t;
        if (node < N) { deg[node] = v; row_start[node] = lo + ex; }
    }
    __syncthreads();
    for (int i = lo + t; i < hi; i += 256) {
        int w = staging[i];
        int p = atomicAdd(&cur[w & 127], 1);
        csr[lo + p] = w >> 7;
    }
}

// ---- layer-1 gather: agg[node] = h[node] + sum_{in-edges} h[src] ----
__global__ __launch_bounds__(256) void gather1(const float* __restrict__ h,
                                               const int* __restrict__ csr,
                                               const int* __restrict__ row_start,
                                               const int* __restrict__ deg,
                                               float* __restrict__ agg) {
    int node = blockIdx.x * 4 + (threadIdx.x >> 6);
    int lane = threadIdx.x & 63;
    float acc = h[node * D + lane];            // self-loop
    int rs = row_start[node], d = deg[node];
    int j = 0;
    for (; j + 4 <= d; j += 4) {
        int s0 = csr[rs + j], s1 = csr[rs + j + 1];
        int s2 = csr[rs + j + 2], s3 = csr[rs + j + 3];
        acc += h[s0 * D + lane];
        acc += h[s1 * D + lane];
        acc += h[s2 * D + lane];
        acc += h[s3 * D + lane];
    }
    for (; j < d; ++j) acc += h[csr[rs + j] * D + lane];
    agg[node * D + lane] = acc;
}

// ---- X = relu(agg @ W1 + b1), tiled ----
__global__ __launch_bounds__(256) void gemm1_relu(const float* __restrict__ A,
                                                  const float* __restrict__ W1,
                                                  const float* __restrict__ b1,
                                                  float* __restrict__ X) {
    __shared__ float w_s[D * H];      // 32 KB, [k][col]
    __shared__ float a_s[16 * D];     // 4 KB,  [row][k]
    int row0 = blockIdx.x * 16;
    {
        const float4* src = (const float4*)W1;
        float4* dst = (float4*)w_s;
#pragma unroll
        for (int i = 0; i < 8; ++i)
            dst[threadIdx.x + i * 256] = src[threadIdx.x + i * 256];
    }
    {
        int r = threadIdx.x >> 4;
        int q = threadIdx.x & 15;
        float4 v = *(const float4*)&A[(row0 + r) * D + q * 4];
        *(float4*)&a_s[r * D + q * 4] = v;
    }
    __syncthreads();

    int tr   = threadIdx.x >> 6;
    int lane = threadIdx.x & 63;
    float acc[4][2] = {};
#pragma unroll
    for (int k = 0; k < D; ++k) {
        float b0 = w_s[k * H + lane];
        float b1v = w_s[k * H + lane + 64];
#pragma unroll
        for (int i = 0; i < 4; ++i) {
            float a = a_s[(tr + 4 * i) * D + k];
            acc[i][0] = fmaf(a, b0, acc[i][0]);
            acc[i][1] = fmaf(a, b1v, acc[i][1]);
        }
    }
    float bias0 = b1[lane], bias1 = b1[lane + 64];
#pragma unroll
    for (int i = 0; i < 4; ++i) {
        int row = row0 + tr + 4 * i;
        X[row * H + lane]      = fmaxf(acc[i][0] + bias0, 0.f);
        X[row * H + lane + 64] = fmaxf(acc[i][1] + bias1, 0.f);
    }
}

// ---- Z = X @ W2, tiled ----
constexpr int XS = 132;
__global__ __launch_bounds__(256) void gemm2(const float* __restrict__ X,
                                             const float* __restrict__ W2,
                                             float* __restrict__ Z) {
    __shared__ float w_s[H * C];        // 20 KB
    __shared__ float x_s[64 * XS];      // 33.8 KB
    int row0 = blockIdx.x * 64;
    {
        const float4* src = (const float4*)W2;
        float4* dst = (float4*)w_s;
#pragma unroll
        for (int i = 0; i < 5; ++i)
            dst[threadIdx.x + i * 256] = src[threadIdx.x + i * 256];
    }
    {
#pragma unroll
        for (int i = 0; i < 8; ++i) {
            int idx = threadIdx.x + i * 256;
            int r = idx >> 5;
            int q = idx & 31;
            int grow = row0 + r;
            if (grow >= N) grow = N - 1;
            float4 v = *(const float4*)&X[grow * H + q * 4];
            *(float4*)&x_s[r * XS + q * 4] = v;
        }
    }
    __syncthreads();

    int tc   = threadIdx.x & 7;
    int trow = threadIdx.x >> 3;
    float acc[2][5] = {};
#pragma unroll 4
    for (int k = 0; k < H; ++k) {
        float b[5];
#pragma unroll
        for (int j = 0; j < 5; ++j) b[j] = w_s[k * C + tc * 5 + j];
        float a0 = x_s[(trow * 2) * XS + k];
        float a1 = x_s[(trow * 2 + 1) * XS + k];
#pragma unroll
        for (int j = 0; j < 5; ++j) {
            acc[0][j] = fmaf(a0, b[j], acc[0][j]);
            acc[1][j] = fmaf(a1, b[j], acc[1][j]);
        }
    }
#pragma unroll
    for (int i = 0; i < 2; ++i) {
        int row = row0 + trow * 2 + i;
        if (row < N) {
#pragma unroll
            for (int j = 0; j < 5; ++j)
                Z[row * C + tc * 5 + j] = acc[i][j];
        }
    }
}

// ---- out[node] = softmax(Z[node] + sum Z[src] + b2) ----
__global__ __launch_bounds__(256) void gather2_softmax(const float* __restrict__ Z,
                                                       const int* __restrict__ csr,
                                                       const int* __restrict__ row_start,
                                                       const int* __restrict__ deg,
                                                       const float* __restrict__ b2,
                                                       float* __restrict__ out) {
    int node = blockIdx.x * 4 + (threadIdx.x >> 6);
    int lane = threadIdx.x & 63;
    int rs = row_start[node], d = deg[node];
    float acc = (lane < C) ? Z[node * C + lane] : 0.f;   // self-loop
    int j = 0;
    for (; j + 4 <= d; j += 4) {
        int s0 = csr[rs + j], s1 = csr[rs + j + 1];
        int s2 = csr[rs + j + 2], s3 = csr[rs + j + 3];
        if (lane < C) {
            acc += Z[s0 * C + lane];
            acc += Z[s1 * C + lane];
            acc += Z[s2 * C + lane];
            acc += Z[s3 * C + lane];
        }
    }
    for (; j < d; ++j) {
        int s = csr[rs + j];
        if (lane < C) acc += Z[s * C + lane];
    }
    float v = (lane < C) ? acc + b2[lane] : -INFINITY;
    float m = v;
    for (int off = 32; off; off >>= 1) m = fmaxf(m, __shfl_xor(m, off));
    float ex = (lane < C) ? expf(v - m) : 0.f;
    float ssum = ex;
    for (int off = 32; off; off >>= 1) ssum += __shfl_xor(ssum, off);
    if (lane < C) out[node * C + lane] = ex / ssum;
}

extern "C" void kernel_launch(void* const* d_in, const int* in_sizes, int n_in,
                              void* d_out, int out_size, void* d_ws, size_t ws_size,
                              hipStream_t stream) {
    const float* h   = (const float*)d_in[0];   // N*D
    const int*   adj = (const int*)  d_in[1];   // E*2
    const float* W1  = (const float*)d_in[2];   // D*H
    const float* b1  = (const float*)d_in[3];   // H
    const float* W2  = (const float*)d_in[4];   // H*C
    const float* b2  = (const float*)d_in[5];   // C
    float* out = (float*)d_out;                 // N*C fp32

    // workspace layout (~105.1 MB)
    float* agg1      = (float*)d_ws;                    // N*D
    float* X         = agg1 + (size_t)N * D;            // N*H
    float* Z         = X    + (size_t)N * H;            // N*C
    int*   deg       = (int*)(Z + (size_t)N * C);       // N
    int*   row_start = deg + N;                         // N
    int*   cnt       = row_start + N;                   // NSEG
    int*   segstart  = cnt + NSEG;                      // NSEG+1
    int*   segcur    = segstart + NSEG + 1;             // NSEG
    int*   partial   = segcur + NSEG;                   // NHB*NBUCK
    int*   staging   = partial + NHB * NBUCK;           // E
    int*   csr       = staging + E;                     // E

    histo_cnt  <<<NHB, 256, 0, stream>>>(adj, partial);
    reduce_cnt <<<(NSEG + 255) / 256, 256, 0, stream>>>(partial, cnt);
    scan_seg   <<<1, 1024, 0, stream>>>(cnt, segstart, segcur);
    append_seg <<<NHB, 256, 0, stream>>>(adj, segcur, staging);
    fill_bucket2<<<NBUCK, 256, 0, stream>>>(staging, segstart, deg, row_start, csr);

    gather1        <<<N / 4, 256, 0, stream>>>(h, csr, row_start, deg, agg1);
    gemm1_relu     <<<N / 16, 256, 0, stream>>>(agg1, W1, b1, X);
    gemm2          <<<(N + 63) / 64, 256, 0, stream>>>(X, W2, Z);
    gather2_softmax<<<N / 4, 256, 0, stream>>>(Z, csr, row_start, deg, b2, out);
}

// Round 6
// 336.842 us; speedup vs baseline: 1.3237x; 1.0536x over previous
//
#include <hip/hip_runtime.h>
#include <hip/hip_fp16.h>
#include <math.h>

// GCN: out = softmax( S·relu((S·h)W1 + b1) · W2 + b2 ),  S = in-edge sum + self-loop.
// Round 6: gathers are traffic-bound (bytes/edge x E). Store gathered operands in
// fp16 (fp32 accumulate): h -> HH (128B rows, 2 lines), Z -> ZH fp16 padded to 128B
// row stride (2 lines vs 3.5). Gathers restructured to multi-edge lane groups.

constexpr int N = 100000;
constexpr int E = 1200000;
constexpr int D = 64;    // input dim
constexpr int H = 128;   // hidden
constexpr int C = 40;    // classes
constexpr int NBUCK = (N + 127) / 128;          // 782 dst-buckets of 128 nodes
constexpr int NSEG  = NBUCK * 8;                // 6256 (bucket x replica) segments
constexpr int EBLK  = 2048;                     // edges per histo/append block
constexpr int NHB   = (E + EBLK - 1) / EBLK;    // 586 edge blocks

// ---- h (fp32) -> HH (fp16), row = 64 halves = 128 B ----
__global__ __launch_bounds__(256) void convert_h(const float2* __restrict__ hf,
                                                 __half2* __restrict__ HH) {
    int i = (blockIdx.x * 256 + threadIdx.x) * 4;   // N*32 = 3.2M half2, exact
#pragma unroll
    for (int k = 0; k < 4; ++k) {
        float2 p = hf[i + k];
        HH[i + k] = __floats2half2_rn(p.x, p.y);
    }
}

// ---- per-block LDS bucket histogram, dense dump (no global atomics) ----
__global__ __launch_bounds__(256) void histo_cnt(const int* __restrict__ adj,
                                                 int* __restrict__ partial) {
    __shared__ int cnt[NBUCK];
    for (int i = threadIdx.x; i < NBUCK; i += 256) cnt[i] = 0;
    __syncthreads();
    int base = blockIdx.x * EBLK + threadIdx.x * 8;
    const int2* edges = (const int2*)adj;
#pragma unroll
    for (int i = 0; i < 8; ++i) {
        int e = base + i;
        if (e < E) atomicAdd(&cnt[edges[e].y >> 7], 1);
    }
    __syncthreads();
    int* dst = partial + blockIdx.x * NBUCK;
    for (int i = threadIdx.x; i < NBUCK; i += 256) dst[i] = cnt[i];
}

__global__ __launch_bounds__(256) void reduce_cnt(const int* __restrict__ partial,
                                                  int* __restrict__ cnt) {
    int seg = blockIdx.x * 256 + threadIdx.x;
    if (seg < NSEG) {
        int b = seg >> 3, r = seg & 7;
        int s = 0;
        for (int blk = r; blk < NHB; blk += 8) s += partial[blk * NBUCK + b];
        cnt[seg] = s;
    }
}

__global__ __launch_bounds__(1024) void scan_seg(const int* __restrict__ cnt,
                                                 int* __restrict__ segstart,
                                                 int* __restrict__ segcur) {
    __shared__ int s[1024];
    int t = threadIdx.x;
    int base = t * 7;
    int local[7];
    int sum = 0;
#pragma unroll
    for (int i = 0; i < 7; ++i) {
        int idx = base + i;
        int v = (idx < NSEG) ? cnt[idx] : 0;
        local[i] = sum;
        sum += v;
    }
    s[t] = sum;
    __syncthreads();
    for (int off = 1; off < 1024; off <<= 1) {
        int x = (t >= off) ? s[t - off] : 0;
        __syncthreads();
        s[t] += x;
        __syncthreads();
    }
    int prev = t ? s[t - 1] : 0;
#pragma unroll
    for (int i = 0; i < 7; ++i) {
        int idx = base + i;
        if (idx < NSEG) {
            int v = prev + local[i];
            segstart[idx] = v;
            segcur[idx]   = v;
        }
    }
    if (t == 1023) segstart[NSEG] = s[1023];   // total = E
}

__global__ __launch_bounds__(256) void append_seg(const int* __restrict__ adj,
                                                  int* __restrict__ segcur,
                                                  int* __restrict__ staging) {
    int base = blockIdx.x * EBLK + threadIdx.x * 8;
    int r = blockIdx.x & 7;
    const int2* edges = (const int2*)adj;
#pragma unroll
    for (int i = 0; i < 8; ++i) {
        int e = base + i;
        if (e < E) {
            int2 ed = edges[e];
            int b = ed.y >> 7;
            int p = atomicAdd(&segcur[b * 8 + r], 1);
            staging[p] = (ed.x << 7) | (ed.y & 127);
        }
    }
}

__global__ __launch_bounds__(256) void fill_bucket2(const int* __restrict__ staging,
                                                    const int* __restrict__ segstart,
                                                    int* __restrict__ deg,
                                                    int* __restrict__ row_start,
                                                    int* __restrict__ csr) {
    __shared__ int cnt[128], cur[128], s[128];
    int b = blockIdx.x;
    int t = threadIdx.x;
    if (t < 128) cnt[t] = 0;
    __syncthreads();
    int lo = segstart[b * 8];
    int hi = segstart[b * 8 + 8];
    for (int i = lo + t; i < hi; i += 256)
        atomicAdd(&cnt[staging[i] & 127], 1);
    __syncthreads();
    int v = (t < 128) ? cnt[t] : 0;
    if (t < 128) s[t] = v;
    __syncthreads();
    for (int off = 1; off < 128; off <<= 1) {
        int x = (t < 128 && t >= off) ? s[t - off] : 0;
        __syncthreads();
        if (t < 128) s[t] += x;
        __syncthreads();
    }
    if (t < 128) {
        int ex = s[t] - v;
        cur[t] = ex;
        int node = (b << 7) + t;
        if (node < N) { deg[node] = v; row_start[node] = lo + ex; }
    }
    __syncthreads();
    for (int i = lo + t; i < hi; i += 256) {
        int w = staging[i];
        int p = atomicAdd(&cur[w & 127], 1);
        csr[lo + p] = w >> 7;
    }
}

// ---- layer-1 gather (fp16 rows): two 32-lane groups, each handles alternate edges ----
__global__ __launch_bounds__(256) void gather1(const __half2* __restrict__ HH,
                                               const int* __restrict__ csr,
                                               const int* __restrict__ row_start,
                                               const int* __restrict__ deg,
                                               float2* __restrict__ agg) {
    int node = blockIdx.x * 4 + (threadIdx.x >> 6);
    int lane = threadIdx.x & 63;
    int g  = lane >> 5;        // 0/1
    int fl = lane & 31;        // half2 index: features 2fl, 2fl+1
    int rs = row_start[node], d = deg[node];
    float ax = 0.f, ay = 0.f;
    if (g == 0) {              // self-loop
        float2 v = __half22float2(HH[node * 32 + fl]);
        ax = v.x; ay = v.y;
    }
    int j = g;
    for (; j + 2 < d; j += 4) {
        int i0 = csr[rs + j], i1 = csr[rs + j + 2];
        float2 v0 = __half22float2(HH[i0 * 32 + fl]);
        float2 v1 = __half22float2(HH[i1 * 32 + fl]);
        ax += v0.x + v1.x;
        ay += v0.y + v1.y;
    }
    for (; j < d; j += 2) {
        float2 v = __half22float2(HH[csr[rs + j] * 32 + fl]);
        ax += v.x; ay += v.y;
    }
    ax += __shfl_xor(ax, 32);
    ay += __shfl_xor(ay, 32);
    if (lane < 32) agg[node * 32 + fl] = make_float2(ax, ay);
}

// ---- X = relu(agg @ W1 + b1), tiled ----
__global__ __launch_bounds__(256) void gemm1_relu(const float* __restrict__ A,
                                                  const float* __restrict__ W1,
                                                  const float* __restrict__ b1,
                                                  float* __restrict__ X) {
    __shared__ float w_s[D * H];      // 32 KB
    __shared__ float a_s[16 * D];     // 4 KB
    int row0 = blockIdx.x * 16;
    {
        const float4* src = (const float4*)W1;
        float4* dst = (float4*)w_s;
#pragma unroll
        for (int i = 0; i < 8; ++i)
            dst[threadIdx.x + i * 256] = src[threadIdx.x + i * 256];
    }
    {
        int r = threadIdx.x >> 4;
        int q = threadIdx.x & 15;
        float4 v = *(const float4*)&A[(row0 + r) * D + q * 4];
        *(float4*)&a_s[r * D + q * 4] = v;
    }
    __syncthreads();

    int tr   = threadIdx.x >> 6;
    int lane = threadIdx.x & 63;
    float acc[4][2] = {};
#pragma unroll
    for (int k = 0; k < D; ++k) {
        float b0 = w_s[k * H + lane];
        float b1v = w_s[k * H + lane + 64];
#pragma unroll
        for (int i = 0; i < 4; ++i) {
            float a = a_s[(tr + 4 * i) * D + k];
            acc[i][0] = fmaf(a, b0, acc[i][0]);
            acc[i][1] = fmaf(a, b1v, acc[i][1]);
        }
    }
    float bias0 = b1[lane], bias1 = b1[lane + 64];
#pragma unroll
    for (int i = 0; i < 4; ++i) {
        int row = row0 + tr + 4 * i;
        X[row * H + lane]      = fmaxf(acc[i][0] + bias0, 0.f);
        X[row * H + lane + 64] = fmaxf(acc[i][1] + bias1, 0.f);
    }
}

// ---- ZH = fp16(X @ W2), row stride 64 halves (128 B), cols 40..63 zero-filled ----
constexpr int XS = 132;
__global__ __launch_bounds__(256) void gemm2(const float* __restrict__ X,
                                             const float* __restrict__ W2,
                                             __half* __restrict__ ZH) {
    __shared__ float w_s[H * C];        // 20 KB
    __shared__ float x_s[64 * XS];      // 33.8 KB
    int row0 = blockIdx.x * 64;
    {
        const float4* src = (const float4*)W2;
        float4* dst = (float4*)w_s;
#pragma unroll
        for (int i = 0; i < 5; ++i)
            dst[threadIdx.x + i * 256] = src[threadIdx.x + i * 256];
    }
    {
#pragma unroll
        for (int i = 0; i < 8; ++i) {
            int idx = threadIdx.x + i * 256;
            int r = idx >> 5;
            int q = idx & 31;
            int grow = row0 + r;
            if (grow >= N) grow = N - 1;
            float4 v = *(const float4*)&X[grow * H + q * 4];
            *(float4*)&x_s[r * XS + q * 4] = v;
        }
    }
    __syncthreads();

    int tc   = threadIdx.x & 7;         // cols tc*5 .. tc*5+4
    int trow = threadIdx.x >> 3;        // rows trow*2, trow*2+1
    float acc[2][5] = {};
#pragma unroll 4
    for (int k = 0; k < H; ++k) {
        float b[5];
#pragma unroll
        for (int j = 0; j < 5; ++j) b[j] = w_s[k * C + tc * 5 + j];
        float a0 = x_s[(trow * 2) * XS + k];
        float a1 = x_s[(trow * 2 + 1) * XS + k];
#pragma unroll
        for (int j = 0; j < 5; ++j) {
            acc[0][j] = fmaf(a0, b[j], acc[0][j]);
            acc[1][j] = fmaf(a1, b[j], acc[1][j]);
        }
    }
#pragma unroll
    for (int i = 0; i < 2; ++i) {
        int row = row0 + trow * 2 + i;
        if (row < N) {
#pragma unroll
            for (int j = 0; j < 5; ++j)
                ZH[row * 64 + tc * 5 + j] = __float2half_rn(acc[i][j]);
#pragma unroll
            for (int j = 0; j < 3; ++j)          // pad cols 40..63 -> full-line writes
                ZH[row * 64 + 40 + tc * 3 + j] = __half(0.f);
        }
    }
}

// ---- out[node] = softmax(Z[node] + sum Z[src] + b2); three 20-lane groups ----
__global__ __launch_bounds__(256) void gather2_softmax(const __half2* __restrict__ ZH,
                                                       const int* __restrict__ csr,
                                                       const int* __restrict__ row_start,
                                                       const int* __restrict__ deg,
                                                       const float2* __restrict__ b2,
                                                       float2* __restrict__ out) {
    int node = blockIdx.x * 4 + (threadIdx.x >> 6);
    int lane = threadIdx.x & 63;
    int g  = (lane >= 40) ? 2 : (lane >= 20 ? 1 : 0);   // lanes 60..63 -> g=2? no:
    if (lane >= 60) g = 3;                               // inactive
    int fl = lane - g * 20;                              // half2 index (features 2fl,2fl+1)
    bool active = (g < 3);
    int rs = row_start[node], d = deg[node];
    float ax = 0.f, ay = 0.f;
    if (g == 0) {                                        // self-loop
        float2 v = __half22float2(ZH[node * 32 + fl]);
        ax = v.x; ay = v.y;
    }
    if (active) {
        int j = g;
        for (; j + 3 < d; j += 6) {
            int i0 = csr[rs + j], i1 = csr[rs + j + 3];
            float2 v0 = __half22float2(ZH[i0 * 32 + fl]);
            float2 v1 = __half22float2(ZH[i1 * 32 + fl]);
            ax += v0.x + v1.x;
            ay += v0.y + v1.y;
        }
        for (; j < d; j += 3) {
            float2 v = __half22float2(ZH[csr[rs + j] * 32 + fl]);
            ax += v.x; ay += v.y;
        }
    }
    // combine the three groups into lanes 0..19
    ax += __shfl(ax, (lane + 20) & 63) + __shfl(ax, (lane + 40) & 63);
    ay += __shfl(ay, (lane + 20) & 63) + __shfl(ay, (lane + 40) & 63);
    float vx = -INFINITY, vy = -INFINITY;
    if (lane < 20) {
        float2 bb = b2[lane];
        vx = ax + bb.x;
        vy = ay + bb.y;
    }
    float m = fmaxf(vx, vy);
#pragma unroll
    for (int off = 16; off; off >>= 1) m = fmaxf(m, __shfl_xor(m, off));  // lanes 0..31 closed
    float ex = (lane < 20) ? expf(vx - m) : 0.f;
    float ey = (lane < 20) ? expf(vy - m) : 0.f;
    float ssum = ex + ey;
#pragma unroll
    for (int off = 16; off; off >>= 1) ssum += __shfl_xor(ssum, off);
    if (lane < 20) {
        float inv = 1.f / ssum;
        out[node * 20 + lane] = make_float2(ex * inv, ey * inv);
    }
}

extern "C" void kernel_launch(void* const* d_in, const int* in_sizes, int n_in,
                              void* d_out, int out_size, void* d_ws, size_t ws_size,
                              hipStream_t stream) {
    const float* h   = (const float*)d_in[0];   // N*D
    const int*   adj = (const int*)  d_in[1];   // E*2
    const float* W1  = (const float*)d_in[2];   // D*H
    const float* b1  = (const float*)d_in[3];   // H
    const float* W2  = (const float*)d_in[4];   // H*C
    const float* b2  = (const float*)d_in[5];   // C
    float* out = (float*)d_out;                 // N*C fp32

    // workspace layout (~89 MB), with lifetime-based aliasing:
    //   [0, 25.6 MB): agg1 (gather1->gemm1); ZH (gemm2->gather2) aliases it (agg1 dead)
    //   [25.6, 76.8): X (gemm1->gemm2); HH (convert->gather1) aliases its head (dead before gemm1)
    //   [76.8, ...):  CSR-build ints
    float*   agg1 = (float*)d_ws;                       // N*D fp32
    __half*  ZH   = (__half*)d_ws;                      // N*64 fp16 (aliases agg1)
    float*   X    = agg1 + (size_t)N * D;               // N*H fp32
    __half*  HH   = (__half*)X;                         // N*64 fp16 (aliases X head)
    int* cnt       = (int*)(X + (size_t)N * H);         // NSEG
    int* segstart  = cnt + NSEG;                        // NSEG+1
    int* segcur    = segstart + NSEG + 1;               // NSEG
    int* partial   = segcur + NSEG;                     // NHB*NBUCK
    int* staging   = partial + NHB * NBUCK;             // E
    int* csr       = staging + E;                       // E
    int* deg       = csr + E;                           // N
    int* row_start = deg + N;                           // N

    convert_h  <<<N * 32 / (256 * 4), 256, 0, stream>>>((const float2*)h, (__half2*)HH);
    histo_cnt  <<<NHB, 256, 0, stream>>>(adj, partial);
    reduce_cnt <<<(NSEG + 255) / 256, 256, 0, stream>>>(partial, cnt);
    scan_seg   <<<1, 1024, 0, stream>>>(cnt, segstart, segcur);
    append_seg <<<NHB, 256, 0, stream>>>(adj, segcur, staging);
    fill_bucket2<<<NBUCK, 256, 0, stream>>>(staging, segstart, deg, row_start, csr);

    gather1        <<<N / 4, 256, 0, stream>>>((const __half2*)HH, csr, row_start, deg,
                                               (float2*)agg1);
    gemm1_relu     <<<N / 16, 256, 0, stream>>>(agg1, W1, b1, X);
    gemm2          <<<(N + 63) / 64, 256, 0, stream>>>(X, W2, ZH);
    gather2_softmax<<<N / 4, 256, 0, stream>>>((const __half2*)ZH, csr, row_start, deg,
                                               (const float2*)b2, (float2*)out);
}

// Round 7
// 277.356 us; speedup vs baseline: 1.6075x; 1.2145x over previous
//
#include <hip/hip_runtime.h>
#include <hip/hip_fp16.h>
#include <math.h>

// GCN: out = softmax( S·relu((S·h)W1 + b1) · W2 + b2 ),  S = in-edge sum + self-loop.
// Round 7: CSR build rebuilt as a deterministic counting sort (no global atomics).
// Buckets of 1024 dst nodes; per-(block,bucket) runs are ~84 B and written by exactly
// one block -> dense line writeback (append WRITE 44.6 -> ~7 MB predicted).

constexpr int N = 100000;
constexpr int E = 1200000;
constexpr int D = 64;    // input dim
constexpr int H = 128;   // hidden
constexpr int C = 40;    // classes
constexpr int NBUCK2 = 98;                      // buckets of 1024 dst nodes (98*1024 >= N)
constexpr int EBLK   = 2048;                    // edges per histo/append block
constexpr int NHB    = (E + EBLK - 1) / EBLK;   // 586 edge blocks

// ---- h (fp32) -> HH (fp16), row = 64 halves = 128 B ----
__global__ __launch_bounds__(256) void convert_h(const float2* __restrict__ hf,
                                                 __half2* __restrict__ HH) {
    int i = (blockIdx.x * 256 + threadIdx.x) * 4;   // N*32 = 3.2M half2, exact
#pragma unroll
    for (int k = 0; k < 4; ++k) {
        float2 p = hf[i + k];
        HH[i + k] = __floats2half2_rn(p.x, p.y);
    }
}

// ---- per-block LDS bucket histogram (98 buckets), dense partial dump ----
__global__ __launch_bounds__(256) void histo_b(const int2* __restrict__ edges,
                                               int* __restrict__ partial) {
    __shared__ int cnt[NBUCK2];
    if (threadIdx.x < NBUCK2) cnt[threadIdx.x] = 0;
    __syncthreads();
    int base = blockIdx.x * EBLK + threadIdx.x * 8;
#pragma unroll
    for (int i = 0; i < 8; ++i) {
        int e = base + i;
        if (e < E) atomicAdd(&cnt[edges[e].y >> 10], 1);
    }
    __syncthreads();
    if (threadIdx.x < NBUCK2)
        partial[blockIdx.x * NBUCK2 + threadIdx.x] = cnt[threadIdx.x];
}

// ---- per-bucket column scan of partial: obase[b][blk] = sum_{blk'<blk}, btot[b] ----
__global__ __launch_bounds__(1024) void scan_pb(const int* __restrict__ partial,
                                                int* __restrict__ obase,
                                                int* __restrict__ btot) {
    __shared__ int s[1024];
    int b = blockIdx.x, t = threadIdx.x;
    int v = (t < NHB) ? partial[t * NBUCK2 + b] : 0;
    s[t] = v;
    __syncthreads();
    for (int off = 1; off < 1024; off <<= 1) {
        int x = (t >= off) ? s[t - off] : 0;
        __syncthreads();
        s[t] += x;
        __syncthreads();
    }
    if (t < NHB) obase[b * NHB + t] = s[t] - v;   // exclusive within bucket
    if (t == 1023) btot[b] = s[1023];
}

// ---- exclusive scan of bucket totals -> bstart[0..NBUCK2] ----
__global__ __launch_bounds__(128) void scan_bt(const int* __restrict__ btot,
                                               int* __restrict__ bstart) {
    __shared__ int s[128];
    int t = threadIdx.x;
    int v = (t < NBUCK2) ? btot[t] : 0;
    s[t] = v;
    __syncthreads();
    for (int off = 1; off < 128; off <<= 1) {
        int x = (t >= off) ? s[t - off] : 0;
        __syncthreads();
        s[t] += x;
        __syncthreads();
    }
    if (t < NBUCK2) bstart[t] = s[t] - v;
    if (t == NBUCK2 - 1) bstart[NBUCK2] = s[t];   // = E
}

// ---- append: deterministic positions, LDS cursors seeded from scanned bases ----
__global__ __launch_bounds__(256) void append_b(const int2* __restrict__ edges,
                                                const int* __restrict__ bstart,
                                                const int* __restrict__ obase,
                                                int* __restrict__ staging) {
    __shared__ int cur[NBUCK2];
    int blk = blockIdx.x;
    if (threadIdx.x < NBUCK2)
        cur[threadIdx.x] = bstart[threadIdx.x] + obase[threadIdx.x * NHB + blk];
    __syncthreads();
    int base = blk * EBLK + threadIdx.x * 8;
#pragma unroll
    for (int i = 0; i < 8; ++i) {
        int e = base + i;
        if (e < E) {
            int2 ed = edges[e];
            int b = ed.y >> 10;
            int p = atomicAdd(&cur[b], 1);          // LDS atomic
            staging[p] = (ed.x << 10) | (ed.y & 1023);   // src:17b | dst_local:10b
        }
    }
}

// ---- per-bucket: LDS count + scan -> deg/row_start, scatter csr in 49 KB window ----
__global__ __launch_bounds__(1024) void fill_b(const int* __restrict__ staging,
                                               const int* __restrict__ bstart,
                                               int* __restrict__ deg,
                                               int* __restrict__ row_start,
                                               int* __restrict__ csr) {
    __shared__ int cnt[1024], s[1024], cur[1024];
    int b = blockIdx.x, t = threadIdx.x;
    cnt[t] = 0;
    __syncthreads();
    int lo = bstart[b], hi = bstart[b + 1];
    for (int i = lo + t; i < hi; i += 1024)
        atomicAdd(&cnt[staging[i] & 1023], 1);
    __syncthreads();
    int v = cnt[t];
    s[t] = v;
    __syncthreads();
    for (int off = 1; off < 1024; off <<= 1) {
        int x = (t >= off) ? s[t - off] : 0;
        __syncthreads();
        s[t] += x;
        __syncthreads();
    }
    int ex = s[t] - v;
    cur[t] = ex;
    int node = (b << 10) + t;
    if (node < N) { deg[node] = v; row_start[node] = lo + ex; }
    __syncthreads();
    for (int i = lo + t; i < hi; i += 1024) {
        int w = staging[i];
        int p = atomicAdd(&cur[w & 1023], 1);
        csr[lo + p] = w >> 10;
    }
}

// ---- layer-1 gather (fp16 rows): two 32-lane groups over alternate edges ----
__global__ __launch_bounds__(256) void gather1(const __half2* __restrict__ HH,
                                               const int* __restrict__ csr,
                                               const int* __restrict__ row_start,
                                               const int* __restrict__ deg,
                                               float2* __restrict__ agg) {
    int node = blockIdx.x * 4 + (threadIdx.x >> 6);
    int lane = threadIdx.x & 63;
    int g  = lane >> 5;        // 0/1
    int fl = lane & 31;        // half2 index: features 2fl, 2fl+1
    int rs = row_start[node], d = deg[node];
    float ax = 0.f, ay = 0.f;
    if (g == 0) {              // self-loop
        float2 v = __half22float2(HH[node * 32 + fl]);
        ax = v.x; ay = v.y;
    }
    int j = g;
    for (; j + 2 < d; j += 4) {
        int i0 = csr[rs + j], i1 = csr[rs + j + 2];
        float2 v0 = __half22float2(HH[i0 * 32 + fl]);
        float2 v1 = __half22float2(HH[i1 * 32 + fl]);
        ax += v0.x + v1.x;
        ay += v0.y + v1.y;
    }
    for (; j < d; j += 2) {
        float2 v = __half22float2(HH[csr[rs + j] * 32 + fl]);
        ax += v.x; ay += v.y;
    }
    ax += __shfl_xor(ax, 32);
    ay += __shfl_xor(ay, 32);
    if (lane < 32) agg[node * 32 + fl] = make_float2(ax, ay);
}

// ---- X = relu(agg @ W1 + b1), tiled ----
__global__ __launch_bounds__(256) void gemm1_relu(const float* __restrict__ A,
                                                  const float* __restrict__ W1,
                                                  const float* __restrict__ b1,
                                                  float* __restrict__ X) {
    __shared__ float w_s[D * H];      // 32 KB
    __shared__ float a_s[16 * D];     // 4 KB
    int row0 = blockIdx.x * 16;
    {
        const float4* src = (const float4*)W1;
        float4* dst = (float4*)w_s;
#pragma unroll
        for (int i = 0; i < 8; ++i)
            dst[threadIdx.x + i * 256] = src[threadIdx.x + i * 256];
    }
    {
        int r = threadIdx.x >> 4;
        int q = threadIdx.x & 15;
        float4 v = *(const float4*)&A[(row0 + r) * D + q * 4];
        *(float4*)&a_s[r * D + q * 4] = v;
    }
    __syncthreads();

    int tr   = threadIdx.x >> 6;
    int lane = threadIdx.x & 63;
    float acc[4][2] = {};
#pragma unroll
    for (int k = 0; k < D; ++k) {
        float b0 = w_s[k * H + lane];
        float b1v = w_s[k * H + lane + 64];
#pragma unroll
        for (int i = 0; i < 4; ++i) {
            float a = a_s[(tr + 4 * i) * D + k];
            acc[i][0] = fmaf(a, b0, acc[i][0]);
            acc[i][1] = fmaf(a, b1v, acc[i][1]);
        }
    }
    float bias0 = b1[lane], bias1 = b1[lane + 64];
#pragma unroll
    for (int i = 0; i < 4; ++i) {
        int row = row0 + tr + 4 * i;
        X[row * H + lane]      = fmaxf(acc[i][0] + bias0, 0.f);
        X[row * H + lane + 64] = fmaxf(acc[i][1] + bias1, 0.f);
    }
}

// ---- ZH = fp16(X @ W2), row stride 64 halves (128 B), cols 40..63 zero-filled ----
constexpr int XS = 132;
__global__ __launch_bounds__(256) void gemm2(const float* __restrict__ X,
                                             const float* __restrict__ W2,
                                             __half* __restrict__ ZH) {
    __shared__ float w_s[H * C];        // 20 KB
    __shared__ float x_s[64 * XS];      // 33.8 KB
    int row0 = blockIdx.x * 64;
    {
        const float4* src = (const float4*)W2;
        float4* dst = (float4*)w_s;
#pragma unroll
        for (int i = 0; i < 5; ++i)
            dst[threadIdx.x + i * 256] = src[threadIdx.x + i * 256];
    }
    {
#pragma unroll
        for (int i = 0; i < 8; ++i) {
            int idx = threadIdx.x + i * 256;
            int r = idx >> 5;
            int q = idx & 31;
            int grow = row0 + r;
            if (grow >= N) grow = N - 1;
            float4 v = *(const float4*)&X[grow * H + q * 4];
            *(float4*)&x_s[r * XS + q * 4] = v;
        }
    }
    __syncthreads();

    int tc   = threadIdx.x & 7;         // cols tc*5 .. tc*5+4
    int trow = threadIdx.x >> 3;        // rows trow*2, trow*2+1
    float acc[2][5] = {};
#pragma unroll 4
    for (int k = 0; k < H; ++k) {
        float b[5];
#pragma unroll
        for (int j = 0; j < 5; ++j) b[j] = w_s[k * C + tc * 5 + j];
        float a0 = x_s[(trow * 2) * XS + k];
        float a1 = x_s[(trow * 2 + 1) * XS + k];
#pragma unroll
        for (int j = 0; j < 5; ++j) {
            acc[0][j] = fmaf(a0, b[j], acc[0][j]);
            acc[1][j] = fmaf(a1, b[j], acc[1][j]);
        }
    }
#pragma unroll
    for (int i = 0; i < 2; ++i) {
        int row = row0 + trow * 2 + i;
        if (row < N) {
#pragma unroll
            for (int j = 0; j < 5; ++j)
                ZH[row * 64 + tc * 5 + j] = __float2half_rn(acc[i][j]);
#pragma unroll
            for (int j = 0; j < 3; ++j)          // pad cols 40..63 -> full-line writes
                ZH[row * 64 + 40 + tc * 3 + j] = __half(0.f);
        }
    }
}

// ---- out[node] = softmax(Z[node] + sum Z[src] + b2); three 20-lane groups ----
__global__ __launch_bounds__(256) void gather2_softmax(const __half2* __restrict__ ZH,
                                                       const int* __restrict__ csr,
                                                       const int* __restrict__ row_start,
                                                       const int* __restrict__ deg,
                                                       const float2* __restrict__ b2,
                                                       float2* __restrict__ out) {
    int node = blockIdx.x * 4 + (threadIdx.x >> 6);
    int lane = threadIdx.x & 63;
    int g  = (lane >= 40) ? 2 : (lane >= 20 ? 1 : 0);
    if (lane >= 60) g = 3;                               // inactive
    int fl = lane - g * 20;                              // half2 index
    bool active = (g < 3);
    int rs = row_start[node], d = deg[node];
    float ax = 0.f, ay = 0.f;
    if (g == 0) {                                        // self-loop
        float2 v = __half22float2(ZH[node * 32 + fl]);
        ax = v.x; ay = v.y;
    }
    if (active) {
        int j = g;
        for (; j + 3 < d; j += 6) {
            int i0 = csr[rs + j], i1 = csr[rs + j + 3];
            float2 v0 = __half22float2(ZH[i0 * 32 + fl]);
            float2 v1 = __half22float2(ZH[i1 * 32 + fl]);
            ax += v0.x + v1.x;
            ay += v0.y + v1.y;
        }
        for (; j < d; j += 3) {
            float2 v = __half22float2(ZH[csr[rs + j] * 32 + fl]);
            ax += v.x; ay += v.y;
        }
    }
    ax += __shfl(ax, (lane + 20) & 63) + __shfl(ax, (lane + 40) & 63);
    ay += __shfl(ay, (lane + 20) & 63) + __shfl(ay, (lane + 40) & 63);
    float vx = -INFINITY, vy = -INFINITY;
    if (lane < 20) {
        float2 bb = b2[lane];
        vx = ax + bb.x;
        vy = ay + bb.y;
    }
    float m = fmaxf(vx, vy);
#pragma unroll
    for (int off = 16; off; off >>= 1) m = fmaxf(m, __shfl_xor(m, off));
    float ex = (lane < 20) ? expf(vx - m) : 0.f;
    float ey = (lane < 20) ? expf(vy - m) : 0.f;
    float ssum = ex + ey;
#pragma unroll
    for (int off = 16; off; off >>= 1) ssum += __shfl_xor(ssum, off);
    if (lane < 20) {
        float inv = 1.f / ssum;
        out[node * 20 + lane] = make_float2(ex * inv, ey * inv);
    }
}

extern "C" void kernel_launch(void* const* d_in, const int* in_sizes, int n_in,
                              void* d_out, int out_size, void* d_ws, size_t ws_size,
                              hipStream_t stream) {
    const float* h   = (const float*)d_in[0];   // N*D
    const int*   adj = (const int*)  d_in[1];   // E*2
    const float* W1  = (const float*)d_in[2];   // D*H
    const float* b1  = (const float*)d_in[3];   // H
    const float* W2  = (const float*)d_in[4];   // H*C
    const float* b2  = (const float*)d_in[5];   // C
    float* out = (float*)d_out;                 // N*C fp32

    // workspace layout (~88 MB), lifetime aliasing:
    //   [0, 25.6 MB): agg1 (gather1->gemm1); ZH (gemm2->gather2) aliases it
    //   [25.6, 76.8): X (gemm1->gemm2); HH (convert->gather1) aliases its head
    //   [76.8, ...):  CSR-build ints
    float*   agg1 = (float*)d_ws;                       // N*D fp32
    __half*  ZH   = (__half*)d_ws;                      // N*64 fp16 (aliases agg1)
    float*   X    = agg1 + (size_t)N * D;               // N*H fp32
    __half*  HH   = (__half*)X;                         // N*64 fp16 (aliases X head)
    int* partial   = (int*)(X + (size_t)N * H);         // NHB*NBUCK2
    int* obase     = partial + NHB * NBUCK2;            // NBUCK2*NHB
    int* btot      = obase + NBUCK2 * NHB;              // 128
    int* bstart    = btot + 128;                        // NBUCK2+1 (pad 128)
    int* staging   = bstart + 128;                      // E
    int* csr       = staging + E;                       // E
    int* deg       = csr + E;                           // N
    int* row_start = deg + N;                           // N

    convert_h<<<N * 32 / (256 * 4), 256, 0, stream>>>((const float2*)h, (__half2*)HH);
    histo_b  <<<NHB, 256, 0, stream>>>((const int2*)adj, partial);
    scan_pb  <<<NBUCK2, 1024, 0, stream>>>(partial, obase, btot);
    scan_bt  <<<1, 128, 0, stream>>>(btot, bstart);
    append_b <<<NHB, 256, 0, stream>>>((const int2*)adj, bstart, obase, staging);
    fill_b   <<<NBUCK2, 1024, 0, stream>>>(staging, bstart, deg, row_start, csr);

    gather1        <<<N / 4, 256, 0, stream>>>((const __half2*)HH, csr, row_start, deg,
                                               (float2*)agg1);
    gemm1_relu     <<<N / 16, 256, 0, stream>>>(agg1, W1, b1, X);
    gemm2          <<<(N + 63) / 64, 256, 0, stream>>>(X, W2, ZH);
    gather2_softmax<<<N / 4, 256, 0, stream>>>((const __half2*)ZH, csr, row_start, deg,
                                               (const float2*)b2, (float2*)out);
}